// Round 15
// baseline (94.021 us; speedup 1.0000x reference)
//
#include <hip/hip_runtime.h>
#include <hip/hip_bf16.h>

#define NODES   50000
#define EDGES   1600000
#define DIM     128
#define NB      391        // buckets of 128 nodes
#define BSTRIDE 4608       // fixed bucket capacity (mean 4092, +8 sigma)
#define TILE    8192
#define EPT     32
#define NTILES  196
#define ZROW    50000      // zero sentinel row in y2 (rows 50000..50047 zeroed by gemm)

typedef unsigned int   u32;
typedef unsigned short u16;
typedef __attribute__((ext_vector_type(4))) float f32x4;
typedef __attribute__((ext_vector_type(8))) short s16x8;

__device__ inline u16 f2bf(float f) {
  __hip_bfloat16 h = __float2bfloat16(f);
  return *reinterpret_cast<u16*>(&h);
}

// ---------------- bin pass A (+ W-prep in blocks 0..3): edges -> bucket regions ----------------
__global__ __launch_bounds__(256) void k_binA(const int* __restrict__ erow,
                                              const int* __restrict__ ecol,
                                              const float* __restrict__ W,
                                              u16* __restrict__ wts,
                                              int* __restrict__ gcursor,
                                              u32* __restrict__ binned) {
  __shared__ int hist[NB];
  __shared__ int lcur[NB];
  __shared__ float T[32 * 132];     // prep scratch (blocks 0..3 only)
  int t = threadIdx.x;

  // ---- merged W-prep: blocks 0..3 transpose+swizzle 32 cols each ----
  if (blockIdx.x < 4) {
    int c0 = blockIdx.x * 32;
#pragma unroll
    for (int i = 0; i < 16; ++i) {
      int idx = i * 256 + t;        // 4096 = 128k x 32c
      int k = idx >> 5;
      int cc = idx & 31;
      T[cc * 132 + k] = W[k * 128 + c0 + cc];
    }
    __syncthreads();
#pragma unroll
    for (int i = 0; i < 2; ++i) {
      int idx = i * 256 + t;        // 512 = 32c x 16 chunks
      int cc = idx >> 4;
      int kc = idx & 15;
      int c = c0 + cc;
      int kbase = kc * 8;
      u32 p[4];
#pragma unroll
      for (int u = 0; u < 4; ++u) {
        float a = T[cc * 132 + kbase + 2 * u];
        float b = T[cc * 132 + kbase + 2 * u + 1];
        p[u] = (u32)f2bf(a) | ((u32)f2bf(b) << 16);
      }
      int off = c * 256 + ((kbase * 2) ^ ((c & 15) << 4));
      *(uint4*)((char*)wts + off) = make_uint4(p[0], p[1], p[2], p[3]);
    }
    __syncthreads();
  }

  // ---- binning ----
  for (int b = t; b < NB; b += 256) hist[b] = 0;
  __syncthreads();
  int base = blockIdx.x * TILE;
  u32 v[EPT];
#pragma unroll
  for (int k = 0; k < 8; ++k) {
    int e4 = base + k * 1024 + t * 4;   // EDGES % 4 == 0 -> full int4 in-bounds when e4 < EDGES
    if (e4 < EDGES) {
      int4 rr = *(const int4*)&erow[e4];
      int4 cc = *(const int4*)&ecol[e4];
      v[k * 4 + 0] = ((u32)rr.x << 16) | (u32)cc.x;
      v[k * 4 + 1] = ((u32)rr.y << 16) | (u32)cc.y;
      v[k * 4 + 2] = ((u32)rr.z << 16) | (u32)cc.z;
      v[k * 4 + 3] = ((u32)rr.w << 16) | (u32)cc.w;
      atomicAdd(&hist[(u32)rr.x >> 7], 1);
      atomicAdd(&hist[(u32)rr.y >> 7], 1);
      atomicAdd(&hist[(u32)rr.z >> 7], 1);
      atomicAdd(&hist[(u32)rr.w >> 7], 1);
    } else {
      v[k * 4 + 0] = 0xffffffffu;
      v[k * 4 + 1] = 0xffffffffu;
      v[k * 4 + 2] = 0xffffffffu;
      v[k * 4 + 3] = 0xffffffffu;
    }
  }
  __syncthreads();
  for (int b = t; b < NB; b += 256) {
    int h = hist[b];
    lcur[b] = h ? (b * BSTRIDE + atomicAdd(&gcursor[b], h)) : 0;   // gcursor is RELATIVE (memset 0)
  }
  __syncthreads();
#pragma unroll
  for (int k = 0; k < EPT; ++k) {
    if (v[k] != 0xffffffffu) {
      int b = (int)(v[k] >> 23);
      int pos = atomicAdd(&lcur[b], 1);
      if (pos < (b + 1) * BSTRIDE) binned[pos] = v[k];   // overflow clamp (never hit)
    }
  }
}

// ---------------- fused binB + gemm: bucket sort -> rp2/dis/cols, then MFMA for same 128 rows ----------------
__global__ __launch_bounds__(256) void k_bg(const u32* __restrict__ binned,
                                            const int* __restrict__ gcur,
                                            const float* __restrict__ x,
                                            const u16* __restrict__ wts,
                                            int2* __restrict__ rp2,
                                            float* __restrict__ dis,
                                            u16* __restrict__ cols,
                                            u16* __restrict__ y2) {
  __shared__ int cnt[128];
  __shared__ int sc[128];
  __shared__ int lcur[128];
  __shared__ float disl[128];
  __shared__ u16 ws_[128 * 128];    // 32 KB; first 9.2 KB aliased as binB stage
  __shared__ u16 xs_[64 * 128];     // 16 KB
  u16* stage = ws_;

  const int b = blockIdx.x, t = threadIdx.x;
  const int n0 = b << 7;
  const int s = b * BSTRIDE;
  int cntE = gcur[b];                       // relative count
  if (cntE > BSTRIDE) cntE = BSTRIDE;
  const int e = s + cntE;

  // ---- binB phase ----
  if (t < 128) cnt[t] = 0;
  __syncthreads();
  u32 held[18];                      // BSTRIDE/256 = 18
#pragma unroll
  for (int k = 0; k < 18; ++k) {
    int j = s + t + k * 256;
    u32 v = (j < e) ? binned[j] : 0xffffffffu;   // r<50000 -> top half never 0xffff
    held[k] = v;
    if (v != 0xffffffffu) atomicAdd(&cnt[(int)(v >> 16) - n0], 1);
  }
  __syncthreads();
  if (t < 128) sc[t] = cnt[t];
  __syncthreads();
  for (int off = 1; off < 128; off <<= 1) {
    int tmp = (t >= off && t < 128) ? sc[t - off] : 0;
    __syncthreads();
    if (t < 128) sc[t] += tmp;
    __syncthreads();
  }
  if (t < 128) {
    disl[t] = rsqrtf((float)cnt[t]);         // pad rows: inf, masked in epilogue
    int n = n0 + t;
    if (n < NODES) {
      int lexcl = sc[t] - cnt[t];
      rp2[n] = make_int2(s + lexcl, s + lexcl + cnt[t]);
      lcur[t] = lexcl;
      dis[n] = disl[t];
    }
  }
  __syncthreads();
#pragma unroll
  for (int k = 0; k < 18; ++k) {
    u32 v = held[k];
    if (v != 0xffffffffu) {
      int pos = atomicAdd(&lcur[(int)(v >> 16) - n0], 1);
      stage[pos] = (u16)(v & 0xffffu);
    }
  }
  __syncthreads();
  {
    u32* dst = (u32*)(cols + s);             // s = b*4608, even -> aligned
    const u32* src = (const u32*)stage;
    int nw = (cntE + 1) >> 1;
    for (int i = t; i < nw; i += 256) dst[i] = src[i];
  }
  __syncthreads();                           // stage fully consumed before ws_ overwrite

  // ---- gemm phase: rows n0 .. n0+127 (2 x 64-row tiles), W staged once ----
  {
    const uint4* src = (const uint4*)wts;
    uint4* dst = (uint4*)ws_;
#pragma unroll
    for (int i = 0; i < 8; ++i) dst[i * 256 + t] = src[i * 256 + t];
  }
  const int w = t >> 6, l = t & 63, m = l & 15, g = l >> 4;
  const char* xb = (const char*)xs_;
  const char* wb = (const char*)ws_;

#pragma unroll
  for (int tile = 0; tile < 2; ++tile) {
    const int bb = n0 + tile * 64;
    // stage x rows bb..bb+63 (fp32 -> bf16, XOR-swizzled)
#pragma unroll
    for (int i = 0; i < 8; ++i) {
      int goff = i * 4096 + t * 16;
      int row = goff >> 9;
      int gr = bb + row;
      float4 v = make_float4(0.f, 0.f, 0.f, 0.f);
      if (gr < NODES) v = *(const float4*)((const char*)x + (size_t)gr * 512 + (goff & 511));
      u32 lo = (u32)f2bf(v.x) | ((u32)f2bf(v.y) << 16);
      u32 hi = (u32)f2bf(v.z) | ((u32)f2bf(v.w) << 16);
      int colb = (goff & 511) >> 1;
      int off = row * 256 + (colb ^ ((row & 15) << 4));
      *(uint2*)((char*)xs_ + off) = make_uint2(lo, hi);
    }
    __syncthreads();                         // covers ws_ staging (tile 0) + xs_ staging

    f32x4 acc[8];
#pragma unroll
    for (int j = 0; j < 8; ++j) acc[j] = (f32x4)0.0f;
    const int arow = w * 16 + m;
#pragma unroll
    for (int ss = 0; ss < 4; ++ss) {
      int kx = (g * 16 + ss * 64) ^ (m << 4);
      s16x8 a = *(const s16x8*)(xb + arow * 256 + kx);
#pragma unroll
      for (int j = 0; j < 8; ++j) {
        s16x8 bv = *(const s16x8*)(wb + (j * 16 + m) * 256 + kx);
        acc[j] = __builtin_amdgcn_mfma_f32_16x16x32_bf16(a, bv, acc[j], 0, 0, 0);
      }
    }

    // epilogue: scale by disl, zero pad rows (>= NODES)
    int rbase = bb + w * 16 + g * 4;
    int lbase = rbase - n0;
#pragma unroll
    for (int j = 0; j < 8; ++j) {
#pragma unroll
      for (int r = 0; r < 4; ++r) {
        int gr = rbase + r;
        float val = (gr < NODES) ? acc[j][r] * disl[lbase + r] : 0.0f;
        y2[(size_t)gr * 128 + j * 16 + m] = f2bf(val);   // gr <= 50047 < 50048 rows
      }
    }
    __syncthreads();                         // xs_ reads done before next tile restage
  }
}

// ---------------- aggregation: 16 edges in flight per wave (4 groups x 4-deep pipeline) ----------------
__global__ __launch_bounds__(256) void k_agg(const u16* __restrict__ y2,
                                             const int2* __restrict__ rp2,
                                             const u16* __restrict__ cols,
                                             const float* __restrict__ dis,
                                             const float* __restrict__ bias,
                                             float* __restrict__ out) {
  int node = (blockIdx.x * 256 + threadIdx.x) >> 6;
  int l = threadIdx.x & 63;
  if (node >= NODES) return;
  int q = l >> 4;          // which edge within a group of 4
  int m = l & 15;          // 16B chunk within the 256B row
  int2 rr = rp2[node];
  int s = rr.x;
  int e = rr.y;

  float a0 = 0.f, a1 = 0.f, a2 = 0.f, a3 = 0.f;
  float a4 = 0.f, a5 = 0.f, a6 = 0.f, a7 = 0.f;
  const uint4* yb = (const uint4*)y2;

  int c0 = (s + q      < e) ? (int)cols[s + q]      : ZROW;
  int c1 = (s + 4 + q  < e) ? (int)cols[s + 4 + q]  : ZROW;
  int c2 = (s + 8 + q  < e) ? (int)cols[s + 8 + q]  : ZROW;
  int c3 = (s + 12 + q < e) ? (int)cols[s + 12 + q] : ZROW;

  for (int jb = s; jb < e; jb += 16) {
    int nb = jb + 16;
    int d0 = (nb + q      < e) ? (int)cols[nb + q]      : ZROW;
    int d1 = (nb + 4 + q  < e) ? (int)cols[nb + 4 + q]  : ZROW;
    int d2 = (nb + 8 + q  < e) ? (int)cols[nb + 8 + q]  : ZROW;
    int d3 = (nb + 12 + q < e) ? (int)cols[nb + 12 + q] : ZROW;
    uint4 v0 = yb[c0 * 16 + m];
    uint4 v1 = yb[c1 * 16 + m];
    uint4 v2 = yb[c2 * 16 + m];
    uint4 v3 = yb[c3 * 16 + m];
#define ACC(v)                                   \
    a0 += __uint_as_float((v).x << 16);          \
    a1 += __uint_as_float((v).x & 0xffff0000u);  \
    a2 += __uint_as_float((v).y << 16);          \
    a3 += __uint_as_float((v).y & 0xffff0000u);  \
    a4 += __uint_as_float((v).z << 16);          \
    a5 += __uint_as_float((v).z & 0xffff0000u);  \
    a6 += __uint_as_float((v).w << 16);          \
    a7 += __uint_as_float((v).w & 0xffff0000u);
    ACC(v0) ACC(v1) ACC(v2) ACC(v3)
#undef ACC
    c0 = d0; c1 = d1; c2 = d2; c3 = d3;
  }

  a0 += __shfl_xor(a0, 16); a0 += __shfl_xor(a0, 32);
  a1 += __shfl_xor(a1, 16); a1 += __shfl_xor(a1, 32);
  a2 += __shfl_xor(a2, 16); a2 += __shfl_xor(a2, 32);
  a3 += __shfl_xor(a3, 16); a3 += __shfl_xor(a3, 32);
  a4 += __shfl_xor(a4, 16); a4 += __shfl_xor(a4, 32);
  a5 += __shfl_xor(a5, 16); a5 += __shfl_xor(a5, 32);
  a6 += __shfl_xor(a6, 16); a6 += __shfl_xor(a6, 32);
  a7 += __shfl_xor(a7, 16); a7 += __shfl_xor(a7, 32);

  float di = (e > s) ? dis[node] : 0.0f;
  if (q < 2) {
    float r0 = q ? a4 : a0;
    float r1 = q ? a5 : a1;
    float r2 = q ? a6 : a2;
    float r3 = q ? a7 : a3;
    float4 bb = *(const float4*)&bias[m * 8 + q * 4];
    f32x4 o;
    o[0] = bb.x + di * r0;
    o[1] = bb.y + di * r1;
    o[2] = bb.z + di * r2;
    o[3] = bb.w + di * r3;
    __builtin_nontemporal_store(o, (f32x4*)&out[(size_t)node * 128 + m * 8 + q * 4]);
  }
}

extern "C" void kernel_launch(void* const* d_in, const int* in_sizes, int n_in,
                              void* d_out, int out_size, void* d_ws, size_t ws_size,
                              hipStream_t stream) {
  const float* x    = (const float*)d_in[0];
  const float* W    = (const float*)d_in[1];
  const float* bias = (const float*)d_in[2];
  const int*   erow = (const int*)d_in[3];
  const int*   ecol = (const int*)d_in[4];
  float* out = (float*)d_out;

  char* ws = (char*)d_ws;
  int*   gcursor = (int*)(ws + 0);          // 1.6 KB (relative counts, memset 0)
  int2*  rp2     = (int2*)(ws + 4096);      // 400 KB
  float* dis     = (float*)(ws + 409600);   // 200 KB
  u16*   wts     = (u16*)(ws + 614400);     // 32 KB
  u32*   binned  = (u32*)(ws + 655360);     // 391*4608*4 = 7,206,912 B
  u16*   cols    = (u16*)(ws + 7864320);    // 391*4608*2 = 3,603,456 B (+slack)
  u16*   y2      = (u16*)(ws + 11468800);   // 50048 rows * 256 B = 12,812,288 B

  hipMemsetAsync(gcursor, 0, NB * sizeof(int), stream);
  k_binA<<<NTILES, 256, 0, stream>>>(erow, ecol, W, wts, gcursor, binned);
  k_bg<<<NB, 256, 0, stream>>>(binned, gcursor, x, wts, rp2, dis, cols, y2);
  k_agg<<<(NODES * 64 + 255) / 256, 256, 0, stream>>>(y2, rp2, cols, dis, bias, out);
}

// Round 16
// 93.742 us; speedup vs baseline: 1.0030x; 1.0030x over previous
//
#include <hip/hip_runtime.h>
#include <hip/hip_bf16.h>

#define NODES   50000
#define EDGES   1600000
#define DIM     128
#define NB      391        // buckets of 128 nodes
#define BSTRIDE 4608       // fixed bucket capacity (mean 4092, +8 sigma)
#define TILE    4096       // edges per binA block (halved: more blocks, shorter chains)
#define EPT     16
#define NTILES  391        // ceil(1600000/4096)
#define ZROW    50000      // zero sentinel row in y2 (rows 50000..50047 zeroed by gemm)

typedef unsigned int   u32;
typedef unsigned short u16;
typedef __attribute__((ext_vector_type(4))) float f32x4;
typedef __attribute__((ext_vector_type(8))) short s16x8;

__device__ inline u16 f2bf(float f) {
  __hip_bfloat16 h = __float2bfloat16(f);
  return *reinterpret_cast<u16*>(&h);
}

// ---------------- W -> WT bf16 pre-swizzled + gcursor zero (fused) ----------------
__global__ __launch_bounds__(256) void k_prep(const float* __restrict__ W,
                                              u16* __restrict__ wts,
                                              int* __restrict__ gcursor) {
  __shared__ float T[32 * 132];
  int t = threadIdx.x;
  int gi = blockIdx.x * 256 + t;
  if (gi < NB) gcursor[gi] = 0;            // relative counts
  int c0 = blockIdx.x * 32;
#pragma unroll
  for (int i = 0; i < 16; ++i) {
    int idx = i * 256 + t;            // 4096 = 128k x 32c
    int k = idx >> 5;
    int cc = idx & 31;
    T[cc * 132 + k] = W[k * 128 + c0 + cc];
  }
  __syncthreads();
#pragma unroll
  for (int i = 0; i < 2; ++i) {
    int idx = i * 256 + t;            // 512 = 32c x 16 chunks
    int cc = idx >> 4;
    int kc = idx & 15;
    int c = c0 + cc;
    int kbase = kc * 8;
    u32 p[4];
#pragma unroll
    for (int u = 0; u < 4; ++u) {
      float a = T[cc * 132 + kbase + 2 * u];
      float b = T[cc * 132 + kbase + 2 * u + 1];
      p[u] = (u32)f2bf(a) | ((u32)f2bf(b) << 16);
    }
    int off = c * 256 + ((kbase * 2) ^ ((c & 15) << 4));
    *(uint4*)((char*)wts + off) = make_uint4(p[0], p[1], p[2], p[3]);
  }
}

// ---------------- bin pass A: edges -> bucket regions (r,c packed u32), int4 loads ----------------
__global__ __launch_bounds__(256) void k_binA(const int* __restrict__ erow,
                                              const int* __restrict__ ecol,
                                              int* __restrict__ gcursor,
                                              u32* __restrict__ binned) {
  __shared__ int hist[NB];
  __shared__ int lcur[NB];
  int t = threadIdx.x;
  for (int b = t; b < NB; b += 256) hist[b] = 0;
  __syncthreads();
  int base = blockIdx.x * TILE;
  u32 v[EPT];
#pragma unroll
  for (int k = 0; k < 4; ++k) {
    int e4 = base + k * 1024 + t * 4;   // EDGES % 4 == 0 -> full int4 in-bounds when e4 < EDGES
    if (e4 < EDGES) {
      int4 rr = *(const int4*)&erow[e4];
      int4 cc = *(const int4*)&ecol[e4];
      v[k * 4 + 0] = ((u32)rr.x << 16) | (u32)cc.x;
      v[k * 4 + 1] = ((u32)rr.y << 16) | (u32)cc.y;
      v[k * 4 + 2] = ((u32)rr.z << 16) | (u32)cc.z;
      v[k * 4 + 3] = ((u32)rr.w << 16) | (u32)cc.w;
      atomicAdd(&hist[(u32)rr.x >> 7], 1);
      atomicAdd(&hist[(u32)rr.y >> 7], 1);
      atomicAdd(&hist[(u32)rr.z >> 7], 1);
      atomicAdd(&hist[(u32)rr.w >> 7], 1);
    } else {
      v[k * 4 + 0] = 0xffffffffu;
      v[k * 4 + 1] = 0xffffffffu;
      v[k * 4 + 2] = 0xffffffffu;
      v[k * 4 + 3] = 0xffffffffu;
    }
  }
  __syncthreads();
  for (int b = t; b < NB; b += 256) {
    int h = hist[b];
    lcur[b] = h ? (b * BSTRIDE + atomicAdd(&gcursor[b], h)) : 0;
  }
  __syncthreads();
#pragma unroll
  for (int k = 0; k < EPT; ++k) {
    if (v[k] != 0xffffffffu) {
      int b = (int)(v[k] >> 23);
      int pos = atomicAdd(&lcur[b], 1);
      if (pos < (b + 1) * BSTRIDE) binned[pos] = v[k];   // overflow clamp (never hit)
    }
  }
}

// ---------------- bin pass B (512 threads): single read, LDS sort, coalesced cols write ----------------
__global__ __launch_bounds__(512) void k_binB(const u32* __restrict__ binned,
                                              const int* __restrict__ gcur,
                                              int2* __restrict__ rp2,
                                              float* __restrict__ dis,
                                              u16* __restrict__ cols) {
  __shared__ int cnt[128];
  __shared__ int sc[128];
  __shared__ int lcur[128];
  __shared__ u16 stage[BSTRIDE];     // 9216 B
  int b = blockIdx.x;
  int t = threadIdx.x;
  int n0 = b << 7;
  int s = b * BSTRIDE;
  int cntE = gcur[b];                // relative count
  if (cntE > BSTRIDE) cntE = BSTRIDE;
  int e = s + cntE;
  if (t < 128) cnt[t] = 0;
  __syncthreads();
  // hold this thread's edges in registers (static indices), count per node
  u32 held[9];                       // BSTRIDE/512 = 9
#pragma unroll
  for (int k = 0; k < 9; ++k) {
    int j = s + t + k * 512;
    u32 v = (j < e) ? binned[j] : 0xffffffffu;   // r<50000 -> top half never 0xffff
    held[k] = v;
    if (v != 0xffffffffu) atomicAdd(&cnt[(int)(v >> 16) - n0], 1);
  }
  __syncthreads();
  if (t < 128) sc[t] = cnt[t];
  __syncthreads();
  for (int off = 1; off < 128; off <<= 1) {
    int tmp = (t >= off && t < 128) ? sc[t - off] : 0;
    __syncthreads();
    if (t < 128) sc[t] += tmp;
    __syncthreads();
  }
  if (t < 128) {
    int n = n0 + t;
    if (n < NODES) {
      int lexcl = sc[t] - cnt[t];              // local (within bucket)
      rp2[n] = make_int2(s + lexcl, s + lexcl + cnt[t]);
      lcur[t] = lexcl;
      dis[n] = rsqrtf((float)cnt[t]);
    }
  }
  __syncthreads();
#pragma unroll
  for (int k = 0; k < 9; ++k) {
    u32 v = held[k];
    if (v != 0xffffffffu) {
      int pos = atomicAdd(&lcur[(int)(v >> 16) - n0], 1);
      stage[pos] = (u16)(v & 0xffffu);
    }
  }
  __syncthreads();
  // coalesced copy stage[0..cntE) -> cols[s..)
  {
    u32* dst = (u32*)(cols + s);               // s even -> 4B aligned
    const u32* src = (const u32*)stage;
    int nw = (cntE + 1) >> 1;
    for (int i = t; i < nw; i += 512) dst[i] = src[i];
  }
}

// ---------------- y2 = diag(dis) * (x @ W) via MFMA, stored bf16 (pad rows zeroed) ----------------
__global__ __launch_bounds__(256) void k_gemm(const float* __restrict__ x,
                                              const u16* __restrict__ wts,
                                              const float* __restrict__ dis,
                                              u16* __restrict__ y2) {
  __shared__ u16 xs[64 * 128];
  __shared__ u16 ws[128 * 128];
  const int t = threadIdx.x;
  const int bb = blockIdx.x * 64;

  {
    const uint4* src = (const uint4*)wts;
    uint4* dst = (uint4*)ws;
#pragma unroll
    for (int i = 0; i < 8; ++i) dst[i * 256 + t] = src[i * 256 + t];
  }
  {
#pragma unroll
    for (int i = 0; i < 8; ++i) {
      int goff = i * 4096 + t * 16;
      int row = goff >> 9;
      int gr = bb + row;
      float4 v = make_float4(0.f, 0.f, 0.f, 0.f);
      if (gr < NODES) v = *(const float4*)((const char*)x + (size_t)gr * 512 + (goff & 511));
      u32 lo = (u32)f2bf(v.x) | ((u32)f2bf(v.y) << 16);
      u32 hi = (u32)f2bf(v.z) | ((u32)f2bf(v.w) << 16);
      int colb = (goff & 511) >> 1;
      int off = row * 256 + (colb ^ ((row & 15) << 4));
      *(uint2*)((char*)xs + off) = make_uint2(lo, hi);
    }
  }
  __syncthreads();

  const int w = t >> 6, l = t & 63, m = l & 15, g = l >> 4;
  f32x4 acc[8];
#pragma unroll
  for (int j = 0; j < 8; ++j) acc[j] = (f32x4)0.0f;

  const char* xb = (const char*)xs;
  const char* wb = (const char*)ws;
  const int arow = w * 16 + m;
#pragma unroll
  for (int s = 0; s < 4; ++s) {
    int kx = (g * 16 + s * 64) ^ (m << 4);
    s16x8 a = *(const s16x8*)(xb + arow * 256 + kx);
#pragma unroll
    for (int j = 0; j < 8; ++j) {
      s16x8 b = *(const s16x8*)(wb + (j * 16 + m) * 256 + kx);
      acc[j] = __builtin_amdgcn_mfma_f32_16x16x32_bf16(a, b, acc[j], 0, 0, 0);
    }
  }

  // epilogue: scale by dis[row]; rows >= NODES (up to 50047) store ZERO -> zero sentinel rows
  int rbase = bb + w * 16 + g * 4;
  float4 d4 = *(const float4*)&dis[rbase];   // dis region padded past 50000 (garbage ok, masked below)
#pragma unroll
  for (int j = 0; j < 8; ++j) {
#pragma unroll
    for (int r = 0; r < 4; ++r) {
      int gr = rbase + r;
      float dv = (r == 0) ? d4.x : (r == 1) ? d4.y : (r == 2) ? d4.z : d4.w;
      float val = (gr < NODES) ? acc[j][r] * dv : 0.0f;
      y2[(size_t)gr * 128 + j * 16 + m] = f2bf(val);   // gr <= 50047 < 50048 rows: in-bounds
    }
  }
}

// ---------------- aggregation: 16 edges in flight per wave (4 groups x 4-deep pipeline) ----------------
__global__ __launch_bounds__(256) void k_agg(const u16* __restrict__ y2,
                                             const int2* __restrict__ rp2,
                                             const u16* __restrict__ cols,
                                             const float* __restrict__ dis,
                                             const float* __restrict__ bias,
                                             float* __restrict__ out) {
  int node = (blockIdx.x * 256 + threadIdx.x) >> 6;
  int l = threadIdx.x & 63;
  if (node >= NODES) return;
  int q = l >> 4;          // which edge within a group of 4
  int m = l & 15;          // 16B chunk within the 256B row
  int2 rr = rp2[node];
  int s = rr.x;
  int e = rr.y;

  float a0 = 0.f, a1 = 0.f, a2 = 0.f, a3 = 0.f;
  float a4 = 0.f, a5 = 0.f, a6 = 0.f, a7 = 0.f;
  const uint4* yb = (const uint4*)y2;

  int c0 = (s + q      < e) ? (int)cols[s + q]      : ZROW;
  int c1 = (s + 4 + q  < e) ? (int)cols[s + 4 + q]  : ZROW;
  int c2 = (s + 8 + q  < e) ? (int)cols[s + 8 + q]  : ZROW;
  int c3 = (s + 12 + q < e) ? (int)cols[s + 12 + q] : ZROW;

  for (int jb = s; jb < e; jb += 16) {
    int nb = jb + 16;
    int d0 = (nb + q      < e) ? (int)cols[nb + q]      : ZROW;
    int d1 = (nb + 4 + q  < e) ? (int)cols[nb + 4 + q]  : ZROW;
    int d2 = (nb + 8 + q  < e) ? (int)cols[nb + 8 + q]  : ZROW;
    int d3 = (nb + 12 + q < e) ? (int)cols[nb + 12 + q] : ZROW;
    uint4 v0 = yb[c0 * 16 + m];
    uint4 v1 = yb[c1 * 16 + m];
    uint4 v2 = yb[c2 * 16 + m];
    uint4 v3 = yb[c3 * 16 + m];
#define ACC(v)                                   \
    a0 += __uint_as_float((v).x << 16);          \
    a1 += __uint_as_float((v).x & 0xffff0000u);  \
    a2 += __uint_as_float((v).y << 16);          \
    a3 += __uint_as_float((v).y & 0xffff0000u);  \
    a4 += __uint_as_float((v).z << 16);          \
    a5 += __uint_as_float((v).z & 0xffff0000u);  \
    a6 += __uint_as_float((v).w << 16);          \
    a7 += __uint_as_float((v).w & 0xffff0000u);
    ACC(v0) ACC(v1) ACC(v2) ACC(v3)
#undef ACC
    c0 = d0; c1 = d1; c2 = d2; c3 = d3;
  }

  a0 += __shfl_xor(a0, 16); a0 += __shfl_xor(a0, 32);
  a1 += __shfl_xor(a1, 16); a1 += __shfl_xor(a1, 32);
  a2 += __shfl_xor(a2, 16); a2 += __shfl_xor(a2, 32);
  a3 += __shfl_xor(a3, 16); a3 += __shfl_xor(a3, 32);
  a4 += __shfl_xor(a4, 16); a4 += __shfl_xor(a4, 32);
  a5 += __shfl_xor(a5, 16); a5 += __shfl_xor(a5, 32);
  a6 += __shfl_xor(a6, 16); a6 += __shfl_xor(a6, 32);
  a7 += __shfl_xor(a7, 16); a7 += __shfl_xor(a7, 32);

  float di = (e > s) ? dis[node] : 0.0f;
  if (q < 2) {
    float r0 = q ? a4 : a0;
    float r1 = q ? a5 : a1;
    float r2 = q ? a6 : a2;
    float r3 = q ? a7 : a3;
    float4 bb = *(const float4*)&bias[m * 8 + q * 4];
    f32x4 o;
    o[0] = bb.x + di * r0;
    o[1] = bb.y + di * r1;
    o[2] = bb.z + di * r2;
    o[3] = bb.w + di * r3;
    __builtin_nontemporal_store(o, (f32x4*)&out[(size_t)node * 128 + m * 8 + q * 4]);
  }
}

extern "C" void kernel_launch(void* const* d_in, const int* in_sizes, int n_in,
                              void* d_out, int out_size, void* d_ws, size_t ws_size,
                              hipStream_t stream) {
  const float* x    = (const float*)d_in[0];
  const float* W    = (const float*)d_in[1];
  const float* bias = (const float*)d_in[2];
  const int*   erow = (const int*)d_in[3];
  const int*   ecol = (const int*)d_in[4];
  float* out = (float*)d_out;

  char* ws = (char*)d_ws;
  int*   gcursor = (int*)(ws + 0);          // 1.6 KB (relative counts, zeroed by prep)
  int2*  rp2     = (int2*)(ws + 4096);      // 400 KB
  float* dis     = (float*)(ws + 409600);   // 200 KB (+pad, gemm reads to 50048)
  u16*   wts     = (u16*)(ws + 614400);     // 32 KB
  u32*   binned  = (u32*)(ws + 655360);     // 391*4608*4 = 7,206,912 B
  u16*   cols    = (u16*)(ws + 7864320);    // 391*4608*2 = 3,603,456 B (+slack)
  u16*   y2      = (u16*)(ws + 11468800);   // 50048 rows * 256 B = 12,812,288 B

  k_prep<<<4, 256, 0, stream>>>(W, wts, gcursor);
  k_binA<<<NTILES, 256, 0, stream>>>(erow, ecol, gcursor, binned);
  k_binB<<<NB, 512, 0, stream>>>(binned, gcursor, rp2, dis, cols);
  k_gemm<<<(NODES + 63) / 64, 256, 0, stream>>>(x, wts, dis, y2);
  k_agg<<<(NODES * 64 + 255) / 256, 256, 0, stream>>>(y2, rp2, cols, dis, bias, out);
}

// Round 18
// 88.578 us; speedup vs baseline: 1.0615x; 1.0583x over previous
//
#include <hip/hip_runtime.h>
#include <hip/hip_bf16.h>

#define NODES   50000
#define EDGES   1600000
#define DIM     128
#define NB      391        // buckets of 128 nodes
#define BSTRIDE 4608       // fixed bucket capacity (mean 4092, +8 sigma)
#define TILE    4096       // edges per binA block
#define EPT     16
#define NTILES  391        // ceil(1600000/4096)
#define ZROW    50000      // zero sentinel row in y2 (rows 50000..50047 zeroed by gemm)

typedef unsigned int   u32;
typedef unsigned short u16;
typedef __attribute__((ext_vector_type(4))) float f32x4;
typedef __attribute__((ext_vector_type(8))) short s16x8;

__device__ inline u16 f2bf(float f) {
  __hip_bfloat16 h = __float2bfloat16(f);
  return *reinterpret_cast<u16*>(&h);
}

// ---------------- W -> WT bf16 pre-swizzled + gcursor zero + dis pad zero ----------------
__global__ __launch_bounds__(256) void k_prep(const float* __restrict__ W,
                                              u16* __restrict__ wts,
                                              int* __restrict__ gcursor,
                                              float* __restrict__ dis) {
  __shared__ float T[32 * 132];
  int t = threadIdx.x;
  int gi = blockIdx.x * 256 + t;
  if (gi < NB) gcursor[gi] = 0;            // relative counts
  if (blockIdx.x == 0 && t < 48) dis[NODES + t] = 0.0f;   // sentinel rows: weight 0
  int c0 = blockIdx.x * 32;
#pragma unroll
  for (int i = 0; i < 16; ++i) {
    int idx = i * 256 + t;            // 4096 = 128k x 32c
    int k = idx >> 5;
    int cc = idx & 31;
    T[cc * 132 + k] = W[k * 128 + c0 + cc];
  }
  __syncthreads();
#pragma unroll
  for (int i = 0; i < 2; ++i) {
    int idx = i * 256 + t;            // 512 = 32c x 16 chunks
    int cc = idx >> 4;
    int kc = idx & 15;
    int c = c0 + cc;
    int kbase = kc * 8;
    u32 p[4];
#pragma unroll
    for (int u = 0; u < 4; ++u) {
      float a = T[cc * 132 + kbase + 2 * u];
      float b = T[cc * 132 + kbase + 2 * u + 1];
      p[u] = (u32)f2bf(a) | ((u32)f2bf(b) << 16);
    }
    int off = c * 256 + ((kbase * 2) ^ ((c & 15) << 4));
    *(uint4*)((char*)wts + off) = make_uint4(p[0], p[1], p[2], p[3]);
  }
}

// ---------------- heterogeneous kernel: blocks 0..390 binA, 391..1172 gemm ----------------
__global__ __launch_bounds__(256) void k_ag(const int* __restrict__ erow,
                                            const int* __restrict__ ecol,
                                            const float* __restrict__ x,
                                            const u16* __restrict__ wts,
                                            int* __restrict__ gcursor,
                                            u32* __restrict__ binned,
                                            u16* __restrict__ y2) {
  __shared__ u16 ws_[128 * 128];   // 32 KB (binA aliases hist/lcur here)
  __shared__ u16 xs_[64 * 128];    // 16 KB
  const int t = threadIdx.x;

  if (blockIdx.x < NTILES) {
    // ================= binA =================
    int* hist = (int*)ws_;
    int* lcur = hist + NB;
    for (int b = t; b < NB; b += 256) hist[b] = 0;
    __syncthreads();
    int base = blockIdx.x * TILE;
    u32 v[EPT];
#pragma unroll
    for (int k = 0; k < 4; ++k) {
      int e4 = base + k * 1024 + t * 4;   // EDGES % 4 == 0 -> full int4 in-bounds
      if (e4 < EDGES) {
        int4 rr = *(const int4*)&erow[e4];
        int4 cc = *(const int4*)&ecol[e4];
        v[k * 4 + 0] = ((u32)rr.x << 16) | (u32)cc.x;
        v[k * 4 + 1] = ((u32)rr.y << 16) | (u32)cc.y;
        v[k * 4 + 2] = ((u32)rr.z << 16) | (u32)cc.z;
        v[k * 4 + 3] = ((u32)rr.w << 16) | (u32)cc.w;
        atomicAdd(&hist[(u32)rr.x >> 7], 1);
        atomicAdd(&hist[(u32)rr.y >> 7], 1);
        atomicAdd(&hist[(u32)rr.z >> 7], 1);
        atomicAdd(&hist[(u32)rr.w >> 7], 1);
      } else {
        v[k * 4 + 0] = 0xffffffffu;
        v[k * 4 + 1] = 0xffffffffu;
        v[k * 4 + 2] = 0xffffffffu;
        v[k * 4 + 3] = 0xffffffffu;
      }
    }
    __syncthreads();
    for (int b = t; b < NB; b += 256) {
      int h = hist[b];
      lcur[b] = h ? (b * BSTRIDE + atomicAdd(&gcursor[b], h)) : 0;
    }
    __syncthreads();
#pragma unroll
    for (int k = 0; k < EPT; ++k) {
      if (v[k] != 0xffffffffu) {
        int b = (int)(v[k] >> 23);
        int pos = atomicAdd(&lcur[b], 1);
        if (pos < (b + 1) * BSTRIDE) binned[pos] = v[k];   // overflow clamp (never hit)
      }
    }
  } else {
    // ================= gemm (dis-free): y2 = bf16(x @ W) =================
    const int bb = (blockIdx.x - NTILES) * 64;
    {
      const uint4* src = (const uint4*)wts;
      uint4* dst = (uint4*)ws_;
#pragma unroll
      for (int i = 0; i < 8; ++i) dst[i * 256 + t] = src[i * 256 + t];
    }
    {
#pragma unroll
      for (int i = 0; i < 8; ++i) {
        int goff = i * 4096 + t * 16;
        int row = goff >> 9;
        int gr = bb + row;
        float4 v = make_float4(0.f, 0.f, 0.f, 0.f);
        if (gr < NODES) v = *(const float4*)((const char*)x + (size_t)gr * 512 + (goff & 511));
        u32 lo = (u32)f2bf(v.x) | ((u32)f2bf(v.y) << 16);
        u32 hi = (u32)f2bf(v.z) | ((u32)f2bf(v.w) << 16);
        int colb = (goff & 511) >> 1;
        int off = row * 256 + (colb ^ ((row & 15) << 4));
        *(uint2*)((char*)xs_ + off) = make_uint2(lo, hi);
      }
    }
    __syncthreads();

    const int w = t >> 6, l = t & 63, m = l & 15, g = l >> 4;
    f32x4 acc[8];
#pragma unroll
    for (int j = 0; j < 8; ++j) acc[j] = (f32x4)0.0f;

    const char* xb = (const char*)xs_;
    const char* wb = (const char*)ws_;
    const int arow = w * 16 + m;
#pragma unroll
    for (int s = 0; s < 4; ++s) {
      int kx = (g * 16 + s * 64) ^ (m << 4);
      s16x8 a = *(const s16x8*)(xb + arow * 256 + kx);
#pragma unroll
      for (int j = 0; j < 8; ++j) {
        s16x8 b = *(const s16x8*)(wb + (j * 16 + m) * 256 + kx);
        acc[j] = __builtin_amdgcn_mfma_f32_16x16x32_bf16(a, b, acc[j], 0, 0, 0);
      }
    }

    int rbase = bb + w * 16 + g * 4;
#pragma unroll
    for (int j = 0; j < 8; ++j) {
#pragma unroll
      for (int r = 0; r < 4; ++r) {
        int gr = rbase + r;
        float val = (gr < NODES) ? acc[j][r] : 0.0f;   // pad rows -> zero sentinel
        y2[(size_t)gr * 128 + j * 16 + m] = f2bf(val); // gr <= 50047 < 50048 rows
      }
    }
  }
}

// ---------------- bin pass B (512 threads): single read, LDS sort, coalesced cols write ----------------
__global__ __launch_bounds__(512) void k_binB(const u32* __restrict__ binned,
                                              const int* __restrict__ gcur,
                                              int2* __restrict__ rp2,
                                              float* __restrict__ dis,
                                              u16* __restrict__ cols) {
  __shared__ int cnt[128];
  __shared__ int sc[128];
  __shared__ int lcur[128];
  __shared__ u16 stage[BSTRIDE];     // 9216 B
  int b = blockIdx.x;
  int t = threadIdx.x;
  int n0 = b << 7;
  int s = b * BSTRIDE;
  int cntE = gcur[b];                // relative count
  if (cntE > BSTRIDE) cntE = BSTRIDE;
  int e = s + cntE;
  if (t < 128) cnt[t] = 0;
  __syncthreads();
  u32 held[9];                       // BSTRIDE/512 = 9
#pragma unroll
  for (int k = 0; k < 9; ++k) {
    int j = s + t + k * 512;
    u32 v = (j < e) ? binned[j] : 0xffffffffu;
    held[k] = v;
    if (v != 0xffffffffu) atomicAdd(&cnt[(int)(v >> 16) - n0], 1);
  }
  __syncthreads();
  if (t < 128) sc[t] = cnt[t];
  __syncthreads();
  for (int off = 1; off < 128; off <<= 1) {
    int tmp = (t >= off && t < 128) ? sc[t - off] : 0;
    __syncthreads();
    if (t < 128) sc[t] += tmp;
    __syncthreads();
  }
  if (t < 128) {
    int n = n0 + t;
    if (n < NODES) {
      int lexcl = sc[t] - cnt[t];
      rp2[n] = make_int2(s + lexcl, s + lexcl + cnt[t]);
      lcur[t] = lexcl;
      dis[n] = rsqrtf((float)cnt[t]);
    }
  }
  __syncthreads();
#pragma unroll
  for (int k = 0; k < 9; ++k) {
    u32 v = held[k];
    if (v != 0xffffffffu) {
      int pos = atomicAdd(&lcur[(int)(v >> 16) - n0], 1);
      stage[pos] = (u16)(v & 0xffffu);
    }
  }
  __syncthreads();
  {
    u32* dst = (u32*)(cols + s);
    const u32* src = (const u32*)stage;
    int nw = (cntE + 1) >> 1;
    for (int i = t; i < nw; i += 512) dst[i] = src[i];
  }
}

// ---------------- aggregation: 16 edges in flight (4 groups x 4-deep), dis applied per edge ----------------
__global__ __launch_bounds__(256) void k_agg(const u16* __restrict__ y2,
                                             const int2* __restrict__ rp2,
                                             const u16* __restrict__ cols,
                                             const float* __restrict__ dis,
                                             const float* __restrict__ bias,
                                             float* __restrict__ out) {
  int node = (blockIdx.x * 256 + threadIdx.x) >> 6;
  int l = threadIdx.x & 63;
  if (node >= NODES) return;
  int q = l >> 4;          // which edge within a group of 4
  int m = l & 15;          // 16B chunk within the 256B row
  int2 rr = rp2[node];
  int s = rr.x;
  int e = rr.y;

  float a0 = 0.f, a1 = 0.f, a2 = 0.f, a3 = 0.f;
  float a4 = 0.f, a5 = 0.f, a6 = 0.f, a7 = 0.f;
  const uint4* yb = (const uint4*)y2;

  int c0 = (s + q      < e) ? (int)cols[s + q]      : ZROW;
  int c1 = (s + 4 + q  < e) ? (int)cols[s + 4 + q]  : ZROW;
  int c2 = (s + 8 + q  < e) ? (int)cols[s + 8 + q]  : ZROW;
  int c3 = (s + 12 + q < e) ? (int)cols[s + 12 + q] : ZROW;

  for (int jb = s; jb < e; jb += 16) {
    int nb = jb + 16;
    int d0 = (nb + q      < e) ? (int)cols[nb + q]      : ZROW;
    int d1 = (nb + 4 + q  < e) ? (int)cols[nb + 4 + q]  : ZROW;
    int d2 = (nb + 8 + q  < e) ? (int)cols[nb + 8 + q]  : ZROW;
    int d3 = (nb + 12 + q < e) ? (int)cols[nb + 12 + q] : ZROW;
    float w0 = dis[c0];
    float w1 = dis[c1];
    float w2 = dis[c2];
    float w3 = dis[c3];
    uint4 v0 = yb[c0 * 16 + m];
    uint4 v1 = yb[c1 * 16 + m];
    uint4 v2 = yb[c2 * 16 + m];
    uint4 v3 = yb[c3 * 16 + m];
#define ACC(v, wt)                                      \
    a0 += (wt) * __uint_as_float((v).x << 16);          \
    a1 += (wt) * __uint_as_float((v).x & 0xffff0000u);  \
    a2 += (wt) * __uint_as_float((v).y << 16);          \
    a3 += (wt) * __uint_as_float((v).y & 0xffff0000u);  \
    a4 += (wt) * __uint_as_float((v).z << 16);          \
    a5 += (wt) * __uint_as_float((v).z & 0xffff0000u);  \
    a6 += (wt) * __uint_as_float((v).w << 16);          \
    a7 += (wt) * __uint_as_float((v).w & 0xffff0000u);
    ACC(v0, w0) ACC(v1, w1) ACC(v2, w2) ACC(v3, w3)
#undef ACC
    c0 = d0; c1 = d1; c2 = d2; c3 = d3;
  }

  a0 += __shfl_xor(a0, 16); a0 += __shfl_xor(a0, 32);
  a1 += __shfl_xor(a1, 16); a1 += __shfl_xor(a1, 32);
  a2 += __shfl_xor(a2, 16); a2 += __shfl_xor(a2, 32);
  a3 += __shfl_xor(a3, 16); a3 += __shfl_xor(a3, 32);
  a4 += __shfl_xor(a4, 16); a4 += __shfl_xor(a4, 32);
  a5 += __shfl_xor(a5, 16); a5 += __shfl_xor(a5, 32);
  a6 += __shfl_xor(a6, 16); a6 += __shfl_xor(a6, 32);
  a7 += __shfl_xor(a7, 16); a7 += __shfl_xor(a7, 32);

  float di = (e > s) ? dis[node] : 0.0f;
  if (q < 2) {
    float r0 = q ? a4 : a0;
    float r1 = q ? a5 : a1;
    float r2 = q ? a6 : a2;
    float r3 = q ? a7 : a3;
    float4 bb = *(const float4*)&bias[m * 8 + q * 4];
    f32x4 o;
    o[0] = bb.x + di * r0;
    o[1] = bb.y + di * r1;
    o[2] = bb.z + di * r2;
    o[3] = bb.w + di * r3;
    __builtin_nontemporal_store(o, (f32x4*)&out[(size_t)node * 128 + m * 8 + q * 4]);
  }
}

extern "C" void kernel_launch(void* const* d_in, const int* in_sizes, int n_in,
                              void* d_out, int out_size, void* d_ws, size_t ws_size,
                              hipStream_t stream) {
  const float* x    = (const float*)d_in[0];
  const float* W    = (const float*)d_in[1];
  const float* bias = (const float*)d_in[2];
  const int*   erow = (const int*)d_in[3];
  const int*   ecol = (const int*)d_in[4];
  float* out = (float*)d_out;

  char* ws = (char*)d_ws;
  int*   gcursor = (int*)(ws + 0);          // 1.6 KB (relative counts, zeroed by prep)
  int2*  rp2     = (int2*)(ws + 4096);      // 400 KB
  float* dis     = (float*)(ws + 409600);   // 200 KB + 192 B pad (50048 floats)
  u16*   wts     = (u16*)(ws + 614400);     // 32 KB
  u32*   binned  = (u32*)(ws + 655360);     // 391*4608*4 = 7,206,912 B
  u16*   cols    = (u16*)(ws + 7864320);    // 391*4608*2 = 3,603,456 B (+slack)
  u16*   y2      = (u16*)(ws + 11468800);   // 50048 rows * 256 B = 12,812,288 B

  k_prep<<<4, 256, 0, stream>>>(W, wts, gcursor, dis);
  k_ag<<<NTILES + (NODES + 63) / 64, 256, 0, stream>>>(erow, ecol, x, wts, gcursor, binned, y2);
  k_binB<<<NB, 512, 0, stream>>>(binned, gcursor, rp2, dis, cols);
  k_agg<<<(NODES * 64 + 255) / 256, 256, 0, stream>>>(y2, rp2, cols, dis, bias, out);
}